// Round 3
// baseline (1066.920 us; speedup 1.0000x reference)
//
#include <hip/hip_runtime.h>

typedef unsigned short u16;
typedef unsigned int u32;
typedef __attribute__((ext_vector_type(4))) float f32x4;
typedef __attribute__((ext_vector_type(4))) u16 u16x4;
typedef __attribute__((ext_vector_type(8))) __bf16 bf16x8;

// Problem dims (fixed by setup_inputs): B=32, S=1024, I=H=1024
#define BDIM 32
#define SDIM 1024
#define HDIM 1024
#define MT (BDIM*SDIM)   // 32768 GEMM rows
#define NT (3*HDIM)      // 3072  GEMM cols
#define KT 1024          // reduction

__device__ __forceinline__ float bf2f(u16 u) {
  u32 x = ((u32)u) << 16;
  return __builtin_bit_cast(float, x);
}
__device__ __forceinline__ u16 f2bf(float f) {
  u32 x = __builtin_bit_cast(u32, f);
  x = x + 0x7fffu + ((x >> 16) & 1u);
  return (u16)(x >> 16);
}

typedef __attribute__((address_space(1))) void gvoid;
typedef __attribute__((address_space(3))) void lvoid;
__device__ __forceinline__ void gload16(const u16* g, u16* l) {
  // wave-uniform LDS base; HW adds lane*16 on the LDS side; global src is per-lane
  __builtin_amdgcn_global_load_lds((gvoid*)g, (lvoid*)l, 16, 0, 0);
}

// ---------------- cast f32 -> bf16, vectorized (16B in / 8B out per lane) ---
__global__ void cast_kernel(const float* __restrict__ in, u16* __restrict__ out, int n4) {
  int idx = blockIdx.x * blockDim.x + threadIdx.x;
  int stride = gridDim.x * blockDim.x;
  const f32x4* in4 = (const f32x4*)in;
  u16x4* out4 = (u16x4*)out;
  for (int i = idx; i < n4; i += stride) {
    f32x4 v = in4[i];
    u16x4 o;
    o[0] = f2bf(v[0]); o[1] = f2bf(v[1]); o[2] = f2bf(v[2]); o[3] = f2bf(v[3]);
    out4[i] = o;
  }
}

// ---------------- bf16 GEMM: C[m][n] = sum_k A[m][k]*W[n][k] + bias[n] ------
// m97 structure: 128x128 tile, BK=32, 4 waves (2x2), global_load_lds width=16.
__global__ __launch_bounds__(256) void gemm_kernel(
    const u16* __restrict__ A,     // MT x KT bf16 (x)
    const u16* __restrict__ W,     // NT x KT bf16 (w)
    const float* __restrict__ bias,// NT
    u16* __restrict__ C)           // MT x NT bf16 (wx)
{
  __shared__ u16 As[128 * 32];
  __shared__ u16 Bs[128 * 32];
  const int tid  = threadIdx.x;
  const int lane = tid & 63;
  const int wave = tid >> 6;

  // XCD-aware bijective swizzle: grid 6144 = 8 * 768
  int bid = blockIdx.x;
  bid = (bid & 7) * 768 + (bid >> 3);
  const int bm = bid / (NT / 128);
  const int bn = bid % (NT / 128);
  const int wm = (wave >> 1) * 64;   // wave's 64x64 sub-tile
  const int wn = (wave & 1) * 64;

  f32x4 acc[4][4] = {};

  // staging decomposition: 8 chunks of 1KB (16 rows x 32 cols bf16); 2 chunks/wave
  const int rsub = lane >> 2;         // 0..15
  const int ksub = (lane & 3) * 8;    // 0,8,16,24
  const int c0 = wave * 2;

  const u16* Ab0 = A + (size_t)(bm * 128 + c0 * 16 + rsub) * KT + ksub;
  const u16* Ab1 = A + (size_t)(bm * 128 + (c0 + 1) * 16 + rsub) * KT + ksub;
  const u16* Wb0 = W + (size_t)(bn * 128 + c0 * 16 + rsub) * KT + ksub;
  const u16* Wb1 = W + (size_t)(bn * 128 + (c0 + 1) * 16 + rsub) * KT + ksub;
  u16* lA0 = &As[c0 * 512];
  u16* lA1 = &As[(c0 + 1) * 512];
  u16* lB0 = &Bs[c0 * 512];
  u16* lB1 = &Bs[(c0 + 1) * 512];

  const int fr = lane & 15;           // fragment row (A) / col (B)
  const int fk = (lane >> 4) * 8;     // fragment k offset

  for (int kt = 0; kt < KT / 32; ++kt) {
    const int k0 = kt * 32;
    gload16(Ab0 + k0, lA0);
    gload16(Ab1 + k0, lA1);
    gload16(Wb0 + k0, lB0);
    gload16(Wb1 + k0, lB1);
    __syncthreads();   // compiler emits vmcnt(0) drain before s_barrier

    bf16x8 av[4], bv[4];
#pragma unroll
    for (int mi = 0; mi < 4; ++mi)
      av[mi] = *(const bf16x8*)&As[(wm + mi * 16 + fr) * 32 + fk];
#pragma unroll
    for (int ni = 0; ni < 4; ++ni)
      bv[ni] = *(const bf16x8*)&Bs[(wn + ni * 16 + fr) * 32 + fk];
#pragma unroll
    for (int mi = 0; mi < 4; ++mi)
#pragma unroll
      for (int ni = 0; ni < 4; ++ni)
        acc[mi][ni] = __builtin_amdgcn_mfma_f32_16x16x32_bf16(av[mi], bv[ni], acc[mi][ni], 0, 0, 0);
    __syncthreads();
  }

  // epilogue: C/D layout col = lane&15, row = (lane>>4)*4 + reg  [m89-verified]
  const int crow  = bm * 128 + wm + (lane >> 4) * 4;
  const int ccol0 = bn * 128 + wn + (lane & 15);
#pragma unroll
  for (int ni = 0; ni < 4; ++ni) {
    const int col = ccol0 + ni * 16;
    const float bb = bias[col];
#pragma unroll
    for (int mi = 0; mi < 4; ++mi) {
#pragma unroll
      for (int v = 0; v < 4; ++v) {
        C[(size_t)(crow + mi * 16 + v) * NT + col] = f2bf(acc[mi][ni][v] + bb);
      }
    }
  }
}

// ---------------- fused scan + output, register-pipelined prefetch ----------
// one lane per (b,h) chain; 512 blocks x 64 threads = 512 waves (2/CU).
// Depth-16 rotating register buffers: ~60 outstanding loads/wave covers the
// ~900cy HBM latency against the ~40cy/step dependent sigmoid chain.
#define PF 16
__global__ __launch_bounds__(64) void scan_kernel(
    const u16* __restrict__ wx,    // (B*S) x 3H bf16
    const u16* __restrict__ xb,    // (B*S) x H  bf16
    const float* __restrict__ vf,
    const float* __restrict__ vr,
    float* __restrict__ h_out,     // (B*S) x H f32
    float* __restrict__ c_last)    // B x H f32
{
  const int lane = threadIdx.x;
  const int bid  = blockIdx.x;          // 0..511
  const int b    = bid >> 4;            // 0..31
  const int h    = ((bid & 15) << 6) + lane;  // 0..1023

  const float vfh = vf[h];
  const float vrh = vr[h];
  const float SC = 1.7320508075688772f; // sqrt(3)

  const u16* pw = wx + (size_t)b * SDIM * NT + h;
  const u16* px = xb + (size_t)b * SDIM * HDIM + h;
  float* ph = h_out + (size_t)b * SDIM * HDIM + h;

  u16 bwf[PF], bwc[PF], bwr[PF], bxv[PF];
#pragma unroll
  for (int j = 0; j < PF; ++j) {
    bwf[j] = pw[(size_t)j * NT];
    bwc[j] = pw[(size_t)j * NT + HDIM];
    bwr[j] = pw[(size_t)j * NT + 2 * HDIM];
    bxv[j] = px[(size_t)j * HDIM];
  }

  float c = 0.0f;
#pragma unroll 16
  for (int t = 0; t < SDIM; ++t) {
    const int s = t & (PF - 1);
    const float wf = bf2f(bwf[s]);
    const float wc = bf2f(bwc[s]);
    const float wr = bf2f(bwr[s]);
    const float xv = bf2f(bxv[s]);

    // prefetch t+PF into the slot just consumed (issues early, fills while
    // the dependent chain below runs)
    const int tn = t + PF;
    if (tn < SDIM) {
      bwf[s] = pw[(size_t)tn * NT];
      bwc[s] = pw[(size_t)tn * NT + HDIM];
      bwr[s] = pw[(size_t)tn * NT + 2 * HDIM];
      bxv[s] = px[(size_t)tn * HDIM];
    }

    const float ef = __expf(-(wf + vfh * c));
    const float f  = 1.0f / (1.0f + ef);
    const float cn = f * (c - wc) + wc;

    const float er = __expf(-(wr + vrh * c));   // uses prev c
    const float r  = 1.0f / (1.0f + er);

    const float xs = xv * SC;
    ph[(size_t)t * HDIM] = r * (cn - xs) + xs;

    c = cn;
  }
  c_last[(size_t)b * HDIM + h] = c;
}

extern "C" void kernel_launch(void* const* d_in, const int* in_sizes, int n_in,
                              void* d_out, int out_size, void* d_ws, size_t ws_size,
                              hipStream_t stream) {
  const float* x  = (const float*)d_in[0];   // 32*1024*1024
  const float* w  = (const float*)d_in[1];   // 3072*1024
  const float* b  = (const float*)d_in[2];   // 3072
  const float* vf = (const float*)d_in[3];   // 1024
  const float* vr = (const float*)d_in[4];   // 1024

  float* out    = (float*)d_out;
  float* h_out  = out;                       // 33554432 f32
  float* c_last = out + (size_t)33554432;    // 32768 f32

  char* ws = (char*)d_ws;
  u16* xb = (u16*)ws;                               // 67108864 B
  u16* wb = (u16*)(ws + 67108864);                  // 6291456 B
  u16* wx = (u16*)(ws + 67108864 + 6291456);        // 201326592 B

  cast_kernel<<<4096, 256, 0, stream>>>(x, xb, (int)(33554432 / 4));
  cast_kernel<<<1024, 256, 0, stream>>>(w, wb, (int)(3145728 / 4));
  gemm_kernel<<<(MT / 128) * (NT / 128), 256, 0, stream>>>(xb, wb, b, wx);
  scan_kernel<<<512, 64, 0, stream>>>(wx, xb, vf, vr, h_out, c_last);
}

// Round 4
// 619.177 us; speedup vs baseline: 1.7231x; 1.7231x over previous
//
#include <hip/hip_runtime.h>

typedef unsigned short u16;
typedef unsigned int u32;
typedef __attribute__((ext_vector_type(4))) float f32x4;
typedef __attribute__((ext_vector_type(4))) u16 u16x4;
typedef __attribute__((ext_vector_type(8))) u16 u16x8;
typedef __attribute__((ext_vector_type(8))) __bf16 bf16x8;

// Problem dims (fixed by setup_inputs): B=32, S=1024, I=H=1024
#define BDIM 32
#define SDIM 1024
#define HDIM 1024
#define MT (BDIM*SDIM)   // 32768 GEMM rows
#define NT (3*HDIM)      // 3072  GEMM cols
#define KT 1024          // reduction

__device__ __forceinline__ float bf2f(u16 u) {
  u32 x = ((u32)u) << 16;
  return __builtin_bit_cast(float, x);
}
__device__ __forceinline__ u16 f2bf(float f) {
  u32 x = __builtin_bit_cast(u32, f);
  x = x + 0x7fffu + ((x >> 16) & 1u);
  return (u16)(x >> 16);
}

typedef __attribute__((address_space(1))) void gvoid;
typedef __attribute__((address_space(3))) void lvoid;
__device__ __forceinline__ void gload16(const u16* g, u16* l) {
  // wave-uniform LDS base; HW adds lane*16 on the LDS side; global src is per-lane
  __builtin_amdgcn_global_load_lds((gvoid*)g, (lvoid*)l, 16, 0, 0);
}

// ---------------- cast f32 -> bf16, vectorized (16B in / 8B out per lane) ---
__global__ void cast_kernel(const float* __restrict__ in, u16* __restrict__ out, int n4) {
  int idx = blockIdx.x * blockDim.x + threadIdx.x;
  int stride = gridDim.x * blockDim.x;
  const f32x4* in4 = (const f32x4*)in;
  u16x4* out4 = (u16x4*)out;
  for (int i = idx; i < n4; i += stride) {
    f32x4 v = in4[i];
    u16x4 o;
    o[0] = f2bf(v[0]); o[1] = f2bf(v[1]); o[2] = f2bf(v[2]); o[3] = f2bf(v[3]);
    out4[i] = o;
  }
}

// ---------------- bf16 GEMM: C[m][n] = sum_k A[m][k]*W[n][k] + bias[n] ------
// m97 structure: 128x128 tile, BK=32, 4 waves (2x2), global_load_lds width=16.
__global__ __launch_bounds__(256) void gemm_kernel(
    const u16* __restrict__ A,     // MT x KT bf16 (x)
    const u16* __restrict__ W,     // NT x KT bf16 (w)
    const float* __restrict__ bias,// NT
    u16* __restrict__ C)           // MT x NT bf16 (wx)
{
  __shared__ u16 As[128 * 32];
  __shared__ u16 Bs[128 * 32];
  const int tid  = threadIdx.x;
  const int lane = tid & 63;
  const int wave = tid >> 6;

  // XCD-aware bijective swizzle: grid 6144 = 8 * 768
  int bid = blockIdx.x;
  bid = (bid & 7) * 768 + (bid >> 3);
  const int bm = bid / (NT / 128);
  const int bn = bid % (NT / 128);
  const int wm = (wave >> 1) * 64;   // wave's 64x64 sub-tile
  const int wn = (wave & 1) * 64;

  f32x4 acc[4][4] = {};

  // staging decomposition: 8 chunks of 1KB (16 rows x 32 cols bf16); 2 chunks/wave
  const int rsub = lane >> 2;         // 0..15
  const int ksub = (lane & 3) * 8;    // 0,8,16,24
  const int c0 = wave * 2;

  const u16* Ab0 = A + (size_t)(bm * 128 + c0 * 16 + rsub) * KT + ksub;
  const u16* Ab1 = A + (size_t)(bm * 128 + (c0 + 1) * 16 + rsub) * KT + ksub;
  const u16* Wb0 = W + (size_t)(bn * 128 + c0 * 16 + rsub) * KT + ksub;
  const u16* Wb1 = W + (size_t)(bn * 128 + (c0 + 1) * 16 + rsub) * KT + ksub;
  u16* lA0 = &As[c0 * 512];
  u16* lA1 = &As[(c0 + 1) * 512];
  u16* lB0 = &Bs[c0 * 512];
  u16* lB1 = &Bs[(c0 + 1) * 512];

  const int fr = lane & 15;           // fragment row (A) / col (B)
  const int fk = (lane >> 4) * 8;     // fragment k offset

  for (int kt = 0; kt < KT / 32; ++kt) {
    const int k0 = kt * 32;
    gload16(Ab0 + k0, lA0);
    gload16(Ab1 + k0, lA1);
    gload16(Wb0 + k0, lB0);
    gload16(Wb1 + k0, lB1);
    __syncthreads();   // compiler emits vmcnt(0) drain before s_barrier

    bf16x8 av[4], bv[4];
#pragma unroll
    for (int mi = 0; mi < 4; ++mi)
      av[mi] = *(const bf16x8*)&As[(wm + mi * 16 + fr) * 32 + fk];
#pragma unroll
    for (int ni = 0; ni < 4; ++ni)
      bv[ni] = *(const bf16x8*)&Bs[(wn + ni * 16 + fr) * 32 + fk];
#pragma unroll
    for (int mi = 0; mi < 4; ++mi)
#pragma unroll
      for (int ni = 0; ni < 4; ++ni)
        acc[mi][ni] = __builtin_amdgcn_mfma_f32_16x16x32_bf16(av[mi], bv[ni], acc[mi][ni], 0, 0, 0);
    __syncthreads();
  }

  // epilogue: C/D layout col = lane&15, row = (lane>>4)*4 + reg  [m89-verified]
  const int crow  = bm * 128 + wm + (lane >> 4) * 4;
  const int ccol0 = bn * 128 + wn + (lane & 15);
#pragma unroll
  for (int ni = 0; ni < 4; ++ni) {
    const int col = ccol0 + ni * 16;
    const float bb = bias[col];
#pragma unroll
    for (int mi = 0; mi < 4; ++mi) {
#pragma unroll
      for (int v = 0; v < 4; ++v) {
        C[(size_t)(crow + mi * 16 + v) * NT + col] = f2bf(acc[mi][ni][v] + bb);
      }
    }
  }
}

// ---------------- fused scan + output, LDS chunk-staged -----------------------
// One wave per block; 512 blocks; block owns 64 chains (one b, h0..h0+63).
// Per chunk of CH=16 timesteps: stage wf/wc/wr/x tiles (16 x 64 bf16 each) via
// 8 reg-staged dwordx4 loads -> LDS double buffer, software-pipelined one chunk
// ahead. Single-wave block: no barriers; LDS ops in-order per wave.
#define CH 16
#define NCH (SDIM/CH)   // 64
__global__ __launch_bounds__(64) void scan_kernel(
    const u16* __restrict__ wx,    // (B*S) x 3H bf16
    const u16* __restrict__ xb,    // (B*S) x H  bf16
    const float* __restrict__ vf,
    const float* __restrict__ vr,
    float* __restrict__ h_out,     // (B*S) x H f32
    float* __restrict__ c_last)    // B x H f32
{
  __shared__ u16 smem[2][4][CH * 64];   // 16 KB
  const int lane = threadIdx.x;
  const int bid  = blockIdx.x;          // 0..511
  const int b    = bid >> 4;            // 0..31
  const int h0   = (bid & 15) << 6;
  const int h    = h0 + lane;

  const float vfh = vf[h];
  const float vrh = vr[h];
  const float SC = 1.7320508075688772f; // sqrt(3)

  // staging: load j (j=0,1) covers t-rows j*8..j*8+7; lane covers row lrow,
  // elems lcol..lcol+7 (16B) of the 64-wide h-slice.
  const int lrow = lane >> 3;           // 0..7
  const int lcol = (lane & 7) * 8;      // 0,8,..,56
  const u16* wxb = wx + (size_t)(b * SDIM) * NT + h0 + lcol;
  const u16* xbb = xb + (size_t)(b * SDIM) * HDIM + h0 + lcol;

  float* ph = h_out + (size_t)(b * SDIM) * HDIM + h;

  u16x8 rg[4][2];

  auto load_chunk = [&](int t0) {
#pragma unroll
    for (int j = 0; j < 2; ++j) {
      const size_t m = (size_t)(t0 + j * 8 + lrow);
      rg[0][j] = *(const u16x8*)(wxb + m * NT);
      rg[1][j] = *(const u16x8*)(wxb + m * NT + HDIM);
      rg[2][j] = *(const u16x8*)(wxb + m * NT + 2 * HDIM);
      rg[3][j] = *(const u16x8*)(xbb + m * HDIM);
    }
  };
  auto write_chunk = [&](int buf) {
#pragma unroll
    for (int a = 0; a < 4; ++a)
#pragma unroll
      for (int j = 0; j < 2; ++j)
        *(u16x8*)&smem[buf][a][j * 512 + lane * 8] = rg[a][j];
  };

  float c = 0.0f;

  auto compute_chunk = [&](int k, int buf) {
    const u16* sf = &smem[buf][0][lane];
    const u16* sw = &smem[buf][1][lane];
    const u16* sr = &smem[buf][2][lane];
    const u16* sx = &smem[buf][3][lane];
    const int t0 = k * CH;
#pragma unroll
    for (int r = 0; r < CH; ++r) {
      const float wf = bf2f(sf[r * 64]);
      const float wc = bf2f(sw[r * 64]);
      const float wr = bf2f(sr[r * 64]);
      const float xv = bf2f(sx[r * 64]);

      const float ef = __expf(-(wf + vfh * c));
      const float f  = 1.0f / (1.0f + ef);
      const float cn = f * (c - wc) + wc;

      const float er = __expf(-(wr + vrh * c));   // uses prev c
      const float rr = 1.0f / (1.0f + er);

      const float xs = xv * SC;
      ph[(size_t)(t0 + r) * HDIM] = rr * (cn - xs) + xs;
      c = cn;
    }
  };

  // prologue
  load_chunk(0);
  write_chunk(0);
  // main loop: prefetch k+1 (global->reg) before computing k; commit to LDS after
  for (int k = 0; k < NCH - 1; ++k) {
    load_chunk((k + 1) * CH);
    compute_chunk(k, k & 1);
    write_chunk((k + 1) & 1);
  }
  compute_chunk(NCH - 1, (NCH - 1) & 1);

  c_last[(size_t)b * HDIM + h] = c;
}

extern "C" void kernel_launch(void* const* d_in, const int* in_sizes, int n_in,
                              void* d_out, int out_size, void* d_ws, size_t ws_size,
                              hipStream_t stream) {
  const float* x  = (const float*)d_in[0];   // 32*1024*1024
  const float* w  = (const float*)d_in[1];   // 3072*1024
  const float* b  = (const float*)d_in[2];   // 3072
  const float* vf = (const float*)d_in[3];   // 1024
  const float* vr = (const float*)d_in[4];   // 1024

  float* out    = (float*)d_out;
  float* h_out  = out;                       // 33554432 f32
  float* c_last = out + (size_t)33554432;    // 32768 f32

  char* ws = (char*)d_ws;
  u16* xb = (u16*)ws;                               // 67108864 B
  u16* wb = (u16*)(ws + 67108864);                  // 6291456 B
  u16* wx = (u16*)(ws + 67108864 + 6291456);        // 201326592 B

  cast_kernel<<<4096, 256, 0, stream>>>(x, xb, (int)(33554432 / 4));
  cast_kernel<<<1024, 256, 0, stream>>>(w, wb, (int)(3145728 / 4));
  gemm_kernel<<<(MT / 128) * (NT / 128), 256, 0, stream>>>(xb, wb, b, wx);
  scan_kernel<<<512, 64, 0, stream>>>(wx, xb, vf, vr, h_out, c_last);
}